// Round 8
// baseline (36.392 us; speedup 1.0000x reference)
//
#include <hip/hip_runtime.h>
#include <hip/hip_bf16.h>

typedef __attribute__((ext_vector_type(4))) float f32x4;
typedef __attribute__((ext_vector_type(8))) short s16x8;

#define GLOBAL_AS __attribute__((address_space(1)))
#define LDS_AS    __attribute__((address_space(3)))
#define QPB 8

// inputs: [3136][64][16] f32, W: [10][64][16][16] f32, out: [3136][10][16] f32.
// Gram-space routing per (pos,n): G = R^T R (MFMA bf16), s0 = (1/64) R^T 1,
// s += G*squash(s) x2, out = squash(s).
//
// R8 = verified R4 structure with ONE change: inp goes straight to registers
// (coalesced dwordx4; quad lanes share e-chunks via DPP quad_perm rotations)
// instead of LDS staging + b128 reads. Everything else is R4 verbatim.

template<int CTRL>
__device__ __forceinline__ float dpp_add(float x) {
    int v = __builtin_amdgcn_update_dpp(0, __float_as_int(x), CTRL, 0xF, 0xF, true);
    return x + __int_as_float(v);
}
template<int CTRL>
__device__ __forceinline__ float dpp_movf(float x) {
    return __int_as_float(__builtin_amdgcn_update_dpp(0, __float_as_int(x), CTRL, 0xF, 0xF, true));
}

__global__ __launch_bounds__(256, 3) void caps_kernel(
    const float* __restrict__ inp,
    const float* __restrict__ W,
    float* __restrict__ out)
{
    const int tid = threadIdx.x;
    const int w   = tid >> 6;
    const int l   = tid & 63;
    const int n   = blockIdx.x / 98;
    const int qg  = blockIdx.x % 98;
    const int q0  = qg * QPB;

    extern __shared__ __align__(16) char smem[];
    char*  res_s = smem;                   // [0,16K): res double buffer (8K each)
    float* W_s   = (float*)(smem + 16384); // [16K,32K): W quarter (prologue only)

    const int i4 = l >> 2;          // row within 16-block
    const int oq = l & 3;           // o-quad / own e-chunk
    const int i_ = w * 16 + i4;     // input capsule 0..63
    const int col = l & 15;
    const int kg  = l >> 4;

    // ---- first inp quad straight to regs (coalesced: 16B/lane)
    // raw[p] = inp[q*4+p][i_][oq*4 .. +3]
    f32x4 raw[4], rawn[4];
#pragma unroll
    for (int p = 0; p < 4; ++p)
        raw[p] = *(const f32x4*)(inp + (size_t)q0 * 4096 + p * 1024 + w * 256 + l * 4);

    // ---- W prologue (R4-verified staging); gather rotation-ordered wrot:
    // wrot[r*4+k] = W[i_][e = ((oq+r)&3)*4 + k][oq*4 .. +3]
    const float* Wn = W + (size_t)n * 16384;
    f32x4 wrot[16];
    for (int k = 0; k < 4; ++k) {
#pragma unroll
        for (int k2 = 0; k2 < 4; ++k2) {
            int d  = k2 * 256 + tid;    // chunk in quarter (16B units)
            int ir = d >> 6;            // row 0..15
            int cd = d & 63;
            int c  = cd ^ (ir & 7);     // inverse swizzle
            __builtin_amdgcn_global_load_lds(
                (const GLOBAL_AS unsigned int*)(Wn + (k * 1024 + ir * 64 + c) * 4),
                (LDS_AS unsigned int*)((char*)W_s + d * 16), 16, 0, 0);
        }
        __syncthreads();
        if (w == k) {
#pragma unroll
            for (int r = 0; r < 4; ++r) {
                int c = (oq + r) & 3;
#pragma unroll
                for (int kk = 0; kk < 4; ++kk) {
                    int e = c * 4 + kk;
                    wrot[r * 4 + kk] =
                        *(const f32x4*)(W_s + i4 * 256 + (((e * 4 + oq) ^ (i4 & 7)) << 2));
                }
            }
        }
        __syncthreads();
    }

    s16x8 ones;
#pragma unroll
    for (int j = 0; j < 8; ++j) ones[j] = (short)0x3F80;  // bf16 1.0

#pragma unroll 2
    for (int t = 0; t < QPB; ++t) {
        const int q = q0 + t;
        char* rbuf = res_s + (t & 1) * 8192;

        // prefetch next quad's inp
        if (t + 1 < QPB) {
#pragma unroll
            for (int p = 0; p < 4; ++p)
                rawn[p] = *(const f32x4*)(inp + (size_t)(q + 1) * 4096 + p * 1024 + w * 256 + l * 4);
        }

        // ---- einsum (f32 FMA): res[p][i_][oq*4+d] = sum_e inp[p][i_][e]*W[i_][e][oq*4+d]
        // own chunk (r=0) + 3 DPP quad rotations deliver all 16 e
#pragma unroll
        for (int p = 0; p < 4; ++p) {
            f32x4 a = raw[p];
            f32x4 acc = (f32x4)0.0f;
#pragma unroll
            for (int kk = 0; kk < 4; ++kk) acc += a[kk] * wrot[kk];
            f32x4 b1;
#pragma unroll
            for (int kk = 0; kk < 4; ++kk) b1[kk] = dpp_movf<0x39>(a[kk]);  // chunk oq+1
#pragma unroll
            for (int kk = 0; kk < 4; ++kk) acc += b1[kk] * wrot[4 + kk];
            f32x4 b2;
#pragma unroll
            for (int kk = 0; kk < 4; ++kk) b2[kk] = dpp_movf<0x4E>(a[kk]);  // chunk oq+2
#pragma unroll
            for (int kk = 0; kk < 4; ++kk) acc += b2[kk] * wrot[8 + kk];
            f32x4 b3;
#pragma unroll
            for (int kk = 0; kk < 4; ++kk) b3[kk] = dpp_movf<0x93>(a[kk]);  // chunk oq+3
#pragma unroll
            for (int kk = 0; kk < 4; ++kk) acc += b3[kk] * wrot[12 + kk];

            // R4-verified bf16 scatter into [p][o][i] (chunk-XOR swizzle)
#pragma unroll
            for (int dd = 0; dd < 4; ++dd) {
                int o = oq * 4 + dd;
                __hip_bfloat16 bb = __float2bfloat16(acc[dd]);
                int byte = p * 2048 + o * 128 + (((i_ >> 3) ^ (o & 7)) << 4) + (i_ & 7) * 2;
                *(unsigned short*)(rbuf + byte) = *(unsigned short*)&bb;
            }
        }

        // one barrier per iter: LDS writes drained; res double-buffer handles reuse
        asm volatile("s_waitcnt lgkmcnt(0)" ::: "memory");
        __builtin_amdgcn_s_barrier();
        asm volatile("" ::: "memory");
        __builtin_amdgcn_sched_barrier(0);

        // ---- phase B (R4 verbatim): wave w -> pos q*4+w
        s16x8 fr0 = *(const s16x8*)(rbuf + w * 2048 + col * 128 + (((kg + 0) ^ (col & 7)) << 4));
        s16x8 fr1 = *(const s16x8*)(rbuf + w * 2048 + col * 128 + (((kg + 4) ^ (col & 7)) << 4));

        f32x4 G  = (f32x4)0.0f;
        f32x4 C2 = (f32x4)0.0f;
        G  = __builtin_amdgcn_mfma_f32_16x16x32_bf16(fr0, fr0, G, 0, 0, 0);
        G  = __builtin_amdgcn_mfma_f32_16x16x32_bf16(fr1, fr1, G, 0, 0, 0);
        C2 = __builtin_amdgcn_mfma_f32_16x16x32_bf16(ones, fr0, C2, 0, 0, 0);
        C2 = __builtin_amdgcn_mfma_f32_16x16x32_bf16(ones, fr1, C2, 0, 0, 0);
        // G reg rr = G[kg*4+rr][col]; C2 = column sums (rows equal)

        float s = C2[0] * (1.0f / 64.0f);

#pragma unroll
        for (int it = 0; it < 2; ++it) {
            float sn = s * s;                // 16-wide sum, DPP only
            sn = dpp_add<0xB1>(sn);
            sn = dpp_add<0x4E>(sn);
            sn = dpp_add<0x124>(sn);
            sn = dpp_add<0x128>(sn);
            float scale = sqrtf(sn) / (1.0f + sn);
            float v = scale * s;
            float v0 = __shfl(v, kg * 4 + 0);
            float v1 = __shfl(v, kg * 4 + 1);
            float v2 = __shfl(v, kg * 4 + 2);
            float v3 = __shfl(v, kg * 4 + 3);
            float acc = G[0] * v0 + G[1] * v1 + G[2] * v2 + G[3] * v3;
            acc += __shfl_xor(acc, 16);
            acc += __shfl_xor(acc, 32);
            s += acc;
        }

        float sn = s * s;
        sn = dpp_add<0xB1>(sn);
        sn = dpp_add<0x4E>(sn);
        sn = dpp_add<0x124>(sn);
        sn = dpp_add<0x128>(sn);
        float scale = sqrtf(sn) / (1.0f + sn);
        float v = scale * s;

        if (l < 16)
            out[((size_t)(q * 4 + w) * 10 + n) * 16 + col] = v;

        if (t + 1 < QPB) {
#pragma unroll
            for (int p = 0; p < 4; ++p) raw[p] = rawn[p];
        }
    }
}

extern "C" void kernel_launch(void* const* d_in, const int* in_sizes, int n_in,
                              void* d_out, int out_size, void* d_ws, size_t ws_size,
                              hipStream_t stream) {
    const float* inp = (const float*)d_in[0];   // [3136][64][16]
    const float* W   = (const float*)d_in[1];   // [10][64][16][16]
    float* out = (float*)d_out;                 // [3136][10][16]

    dim3 grid(980), block(256);
    hipLaunchKernelGGL(caps_kernel, grid, block, 32768, stream, inp, W, out);
}

// Round 9
// 34.421 us; speedup vs baseline: 1.0573x; 1.0573x over previous
//
#include <hip/hip_runtime.h>
#include <hip/hip_bf16.h>

typedef __attribute__((ext_vector_type(4))) float f32x4;
typedef __attribute__((ext_vector_type(8))) short s16x8;

#define QPB 4

// inputs: [3136][64][16] f32, W: [10][64][16][16] f32, out: [3136][10][16] f32.
// Gram-space routing per (pos,n): G = R^T R (MFMA bf16), s0 = (1/64) R^T 1,
// s += G*squash(s) x2, out = squash(s).
//
// R9 = R8's verified einsum/phase-B with: W loaded straight to registers
// (no LDS prologue, no prologue barriers), QPB=4, grid=1960, LDS=16KB.

template<int CTRL>
__device__ __forceinline__ float dpp_add(float x) {
    int v = __builtin_amdgcn_update_dpp(0, __float_as_int(x), CTRL, 0xF, 0xF, true);
    return x + __int_as_float(v);
}
template<int CTRL>
__device__ __forceinline__ float dpp_movf(float x) {
    return __int_as_float(__builtin_amdgcn_update_dpp(0, __float_as_int(x), CTRL, 0xF, 0xF, true));
}

__global__ __launch_bounds__(256, 4) void caps_kernel(
    const float* __restrict__ inp,
    const float* __restrict__ W,
    float* __restrict__ out)
{
    const int tid = threadIdx.x;
    const int w   = tid >> 6;
    const int l   = tid & 63;
    const int n   = blockIdx.x / 196;
    const int qg  = blockIdx.x % 196;
    const int q0  = qg * QPB;

    extern __shared__ __align__(16) char smem[];
    char* res_s = smem;   // res double buffer: 2 x 8KB

    const int i4 = l >> 2;          // row within 16-block
    const int oq = l & 3;           // o-quad / own e-chunk
    const int i_ = w * 16 + i4;     // input capsule 0..63
    const int col = l & 15;
    const int kg  = l >> 4;

    // ---- W straight to regs, rotation-ordered:
    // wrot[r*4+kk] = W[n][i_][e = ((oq+r)&3)*4 + kk][oq*4 .. +3]
    const float* wb = W + (size_t)n * 16384 + i_ * 256 + oq * 4;
    f32x4 wrot[16];
#pragma unroll
    for (int r = 0; r < 4; ++r) {
        int c = (oq + r) & 3;
#pragma unroll
        for (int kk = 0; kk < 4; ++kk)
            wrot[r * 4 + kk] = *(const f32x4*)(wb + (c * 4 + kk) * 16);
    }

    s16x8 ones;
#pragma unroll
    for (int j = 0; j < 8; ++j) ones[j] = (short)0x3F80;  // bf16 1.0

    for (int t = 0; t < QPB; ++t) {
        const int q = q0 + t;
        char* rbuf = res_s + (t & 1) * 8192;

        // coalesced inp quad load (16B/lane): raw[p] = inp[q*4+p][i_][oq*4..+3]
        f32x4 raw[4];
#pragma unroll
        for (int p = 0; p < 4; ++p)
            raw[p] = *(const f32x4*)(inp + (size_t)q * 4096 + p * 1024 + w * 256 + l * 4);

        // ---- einsum (R8 verbatim): own chunk + 3 DPP quad rotations
#pragma unroll
        for (int p = 0; p < 4; ++p) {
            f32x4 a = raw[p];
            f32x4 acc = (f32x4)0.0f;
#pragma unroll
            for (int kk = 0; kk < 4; ++kk) acc += a[kk] * wrot[kk];
            f32x4 b1;
#pragma unroll
            for (int kk = 0; kk < 4; ++kk) b1[kk] = dpp_movf<0x39>(a[kk]);  // chunk oq+1
#pragma unroll
            for (int kk = 0; kk < 4; ++kk) acc += b1[kk] * wrot[4 + kk];
            f32x4 b2;
#pragma unroll
            for (int kk = 0; kk < 4; ++kk) b2[kk] = dpp_movf<0x4E>(a[kk]);  // chunk oq+2
#pragma unroll
            for (int kk = 0; kk < 4; ++kk) acc += b2[kk] * wrot[8 + kk];
            f32x4 b3;
#pragma unroll
            for (int kk = 0; kk < 4; ++kk) b3[kk] = dpp_movf<0x93>(a[kk]);  // chunk oq+3
#pragma unroll
            for (int kk = 0; kk < 4; ++kk) acc += b3[kk] * wrot[12 + kk];

            // bf16 scatter into [p][o][i] (chunk-XOR swizzle) — R4/R8-verified
#pragma unroll
            for (int dd = 0; dd < 4; ++dd) {
                int o = oq * 4 + dd;
                __hip_bfloat16 bb = __float2bfloat16(acc[dd]);
                int byte = p * 2048 + o * 128 + (((i_ >> 3) ^ (o & 7)) << 4) + (i_ & 7) * 2;
                *(unsigned short*)(rbuf + byte) = *(unsigned short*)&bb;
            }
        }

        // one barrier per iter (race-audited with res double-buffer)
        asm volatile("s_waitcnt lgkmcnt(0)" ::: "memory");
        __builtin_amdgcn_s_barrier();
        asm volatile("" ::: "memory");
        __builtin_amdgcn_sched_barrier(0);

        // ---- phase B (R8 verbatim): wave w -> pos q*4+w
        s16x8 fr0 = *(const s16x8*)(rbuf + w * 2048 + col * 128 + (((kg + 0) ^ (col & 7)) << 4));
        s16x8 fr1 = *(const s16x8*)(rbuf + w * 2048 + col * 128 + (((kg + 4) ^ (col & 7)) << 4));

        f32x4 G  = (f32x4)0.0f;
        f32x4 C2 = (f32x4)0.0f;
        G  = __builtin_amdgcn_mfma_f32_16x16x32_bf16(fr0, fr0, G, 0, 0, 0);
        G  = __builtin_amdgcn_mfma_f32_16x16x32_bf16(fr1, fr1, G, 0, 0, 0);
        C2 = __builtin_amdgcn_mfma_f32_16x16x32_bf16(ones, fr0, C2, 0, 0, 0);
        C2 = __builtin_amdgcn_mfma_f32_16x16x32_bf16(ones, fr1, C2, 0, 0, 0);
        // G reg rr = G[kg*4+rr][col]; C2 = column sums (rows equal)

        float s = C2[0] * (1.0f / 64.0f);

#pragma unroll
        for (int it = 0; it < 2; ++it) {
            float sn = s * s;                // 16-wide sum, DPP only
            sn = dpp_add<0xB1>(sn);
            sn = dpp_add<0x4E>(sn);
            sn = dpp_add<0x124>(sn);
            sn = dpp_add<0x128>(sn);
            float scale = sqrtf(sn) / (1.0f + sn);
            float v = scale * s;
            float v0 = __shfl(v, kg * 4 + 0);
            float v1 = __shfl(v, kg * 4 + 1);
            float v2 = __shfl(v, kg * 4 + 2);
            float v3 = __shfl(v, kg * 4 + 3);
            float acc = G[0] * v0 + G[1] * v1 + G[2] * v2 + G[3] * v3;
            acc += __shfl_xor(acc, 16);
            acc += __shfl_xor(acc, 32);
            s += acc;
        }

        float sn = s * s;
        sn = dpp_add<0xB1>(sn);
        sn = dpp_add<0x4E>(sn);
        sn = dpp_add<0x124>(sn);
        sn = dpp_add<0x128>(sn);
        float scale = sqrtf(sn) / (1.0f + sn);
        float v = scale * s;

        if (l < 16)
            out[((size_t)(q * 4 + w) * 10 + n) * 16 + col] = v;
    }
}

extern "C" void kernel_launch(void* const* d_in, const int* in_sizes, int n_in,
                              void* d_out, int out_size, void* d_ws, size_t ws_size,
                              hipStream_t stream) {
    const float* inp = (const float*)d_in[0];   // [3136][64][16]
    const float* W   = (const float*)d_in[1];   // [10][64][16][16]
    float* out = (float*)d_out;                 // [3136][10][16]

    // 10 n * 196 quad-groups (196*4 quads = 784 = 3136/4); 16 KB dyn LDS
    dim3 grid(1960), block(256);
    hipLaunchKernelGGL(caps_kernel, grid, block, 16384, stream, inp, W, out);
}

// Round 10
// 31.651 us; speedup vs baseline: 1.1498x; 1.0875x over previous
//
#include <hip/hip_runtime.h>
#include <hip/hip_bf16.h>

typedef __attribute__((ext_vector_type(4))) float f32x4;
typedef __attribute__((ext_vector_type(8))) short s16x8;

// inputs: [3136][64][16] f32, W: [10][64][16][16] f32, out: [3136][10][16] f32.
// Gram-space routing per (pos,n): G = R^T R (MFMA bf16), s0 = (1/64) R^T 1,
// s += G*squash(s) x2, out = squash(s).
//
// R10 = R9's verified einsum/phase-B, restructured to 2 quads (8 positions)
// per iteration: each wave runs TWO independent routing chains interleaved
// (hides the serial routing latency), 1 barrier per 2 quads, inp for the
// next double-quad issued before the barrier (hidden under phase B).

template<int CTRL>
__device__ __forceinline__ float dpp_add(float x) {
    int v = __builtin_amdgcn_update_dpp(0, __float_as_int(x), CTRL, 0xF, 0xF, true);
    return x + __int_as_float(v);
}
template<int CTRL>
__device__ __forceinline__ float dpp_movf(float x) {
    return __int_as_float(__builtin_amdgcn_update_dpp(0, __float_as_int(x), CTRL, 0xF, 0xF, true));
}

__global__ __launch_bounds__(256, 3) void caps_kernel(
    const float* __restrict__ inp,
    const float* __restrict__ W,
    float* __restrict__ out)
{
    const int tid = threadIdx.x;
    const int w   = tid >> 6;
    const int l   = tid & 63;
    const int n   = blockIdx.x / 196;
    const int qg  = blockIdx.x % 196;
    const int q0  = qg * 4;            // 4 quads per block = 2 double-quad iters

    extern __shared__ __align__(16) char smem[];
    char* res_s = smem;                // res double buffer: 2 x 16KB

    const int i4 = l >> 2;          // row within 16-block
    const int oq = l & 3;           // o-quad / own e-chunk
    const int i_ = w * 16 + i4;     // input capsule 0..63
    const int col = l & 15;
    const int kg  = l >> 4;

    // ---- W straight to regs, rotation-ordered (R9-verified):
    // wrot[r*4+kk] = W[n][i_][e = ((oq+r)&3)*4 + kk][oq*4 .. +3]
    const float* wb = W + (size_t)n * 16384 + i_ * 256 + oq * 4;
    f32x4 wrot[16];
#pragma unroll
    for (int r = 0; r < 4; ++r) {
        int c = (oq + r) & 3;
#pragma unroll
        for (int kk = 0; kk < 4; ++kk)
            wrot[r * 4 + kk] = *(const f32x4*)(wb + (c * 4 + kk) * 16);
    }

    s16x8 ones;
#pragma unroll
    for (int j = 0; j < 8; ++j) ones[j] = (short)0x3F80;  // bf16 1.0

    // ---- first double-quad inp load (coalesced 16B/lane):
    // raw[pp] = inp[(q0)*4 + pp][i_][oq*4 .. +3], pp = 0..7
    f32x4 raw[8];
#pragma unroll
    for (int pp = 0; pp < 8; ++pp)
        raw[pp] = *(const f32x4*)(inp + (size_t)q0 * 4096 + pp * 1024 + w * 256 + l * 4);

#pragma unroll
    for (int t = 0; t < 2; ++t) {
        char* rbuf = res_s + (t & 1) * 16384;
        const int qb = q0 + 2 * t;          // first quad of this double-quad

        // ---- einsum (verified): 8 positions, own chunk + 3 DPP quad rotations
#pragma unroll
        for (int pp = 0; pp < 8; ++pp) {
            f32x4 a = raw[pp];
            f32x4 acc = (f32x4)0.0f;
#pragma unroll
            for (int kk = 0; kk < 4; ++kk) acc += a[kk] * wrot[kk];
            f32x4 b1;
#pragma unroll
            for (int kk = 0; kk < 4; ++kk) b1[kk] = dpp_movf<0x39>(a[kk]);
#pragma unroll
            for (int kk = 0; kk < 4; ++kk) acc += b1[kk] * wrot[4 + kk];
            f32x4 b2;
#pragma unroll
            for (int kk = 0; kk < 4; ++kk) b2[kk] = dpp_movf<0x4E>(a[kk]);
#pragma unroll
            for (int kk = 0; kk < 4; ++kk) acc += b2[kk] * wrot[8 + kk];
            f32x4 b3;
#pragma unroll
            for (int kk = 0; kk < 4; ++kk) b3[kk] = dpp_movf<0x93>(a[kk]);
#pragma unroll
            for (int kk = 0; kk < 4; ++kk) acc += b3[kk] * wrot[12 + kk];

            // bf16 scatter into [pp][o][i] (chunk-XOR swizzle) — verified
#pragma unroll
            for (int dd = 0; dd < 4; ++dd) {
                int o = oq * 4 + dd;
                __hip_bfloat16 bb = __float2bfloat16(acc[dd]);
                int byte = pp * 2048 + o * 128 + (((i_ >> 3) ^ (o & 7)) << 4) + (i_ & 7) * 2;
                *(unsigned short*)(rbuf + byte) = *(unsigned short*)&bb;
            }
        }

        // issue next double-quad loads now; they complete under phase B
        if (t == 0) {
#pragma unroll
            for (int pp = 0; pp < 8; ++pp)
                raw[pp] = *(const f32x4*)(inp + (size_t)(q0 + 2) * 4096 + pp * 1024 + w * 256 + l * 4);
        }

        // one barrier per double-quad (res double-buffered)
        asm volatile("s_waitcnt lgkmcnt(0)" ::: "memory");
        __builtin_amdgcn_s_barrier();
        asm volatile("" ::: "memory");
        __builtin_amdgcn_sched_barrier(0);

        // ---- phase B: wave w handles pp = w (chain 0) and pp = w+4 (chain 1),
        // two independent routing chains interleaved for ILP.
        float s[2];
        f32x4 G[2];
#pragma unroll
        for (int c = 0; c < 2; ++c) {
            const int pp = w + 4 * c;
            s16x8 fr0 = *(const s16x8*)(rbuf + pp * 2048 + col * 128 + (((kg + 0) ^ (col & 7)) << 4));
            s16x8 fr1 = *(const s16x8*)(rbuf + pp * 2048 + col * 128 + (((kg + 4) ^ (col & 7)) << 4));
            f32x4 g  = (f32x4)0.0f;
            f32x4 c2 = (f32x4)0.0f;
            g  = __builtin_amdgcn_mfma_f32_16x16x32_bf16(fr0, fr0, g, 0, 0, 0);
            g  = __builtin_amdgcn_mfma_f32_16x16x32_bf16(fr1, fr1, g, 0, 0, 0);
            c2 = __builtin_amdgcn_mfma_f32_16x16x32_bf16(ones, fr0, c2, 0, 0, 0);
            c2 = __builtin_amdgcn_mfma_f32_16x16x32_bf16(ones, fr1, c2, 0, 0, 0);
            G[c] = g;
            s[c] = c2[0] * (1.0f / 64.0f);
        }

#pragma unroll
        for (int it = 0; it < 2; ++it) {
#pragma unroll
            for (int c = 0; c < 2; ++c) {
                float sn = s[c] * s[c];
                sn = dpp_add<0xB1>(sn);
                sn = dpp_add<0x4E>(sn);
                sn = dpp_add<0x124>(sn);
                sn = dpp_add<0x128>(sn);
                float scale = sqrtf(sn) / (1.0f + sn);
                float v = scale * s[c];
                float v0 = __shfl(v, kg * 4 + 0);
                float v1 = __shfl(v, kg * 4 + 1);
                float v2 = __shfl(v, kg * 4 + 2);
                float v3 = __shfl(v, kg * 4 + 3);
                float acc = G[c][0] * v0 + G[c][1] * v1 + G[c][2] * v2 + G[c][3] * v3;
                acc += __shfl_xor(acc, 16);
                acc += __shfl_xor(acc, 32);
                s[c] += acc;
            }
        }

#pragma unroll
        for (int c = 0; c < 2; ++c) {
            float sn = s[c] * s[c];
            sn = dpp_add<0xB1>(sn);
            sn = dpp_add<0x4E>(sn);
            sn = dpp_add<0x124>(sn);
            sn = dpp_add<0x128>(sn);
            float scale = sqrtf(sn) / (1.0f + sn);
            float v = scale * s[c];
            if (l < 16)
                out[((size_t)((qb + c) * 4 + w) * 10 + n) * 16 + col] = v;
        }
    }
}

extern "C" void kernel_launch(void* const* d_in, const int* in_sizes, int n_in,
                              void* d_out, int out_size, void* d_ws, size_t ws_size,
                              hipStream_t stream) {
    const float* inp = (const float*)d_in[0];   // [3136][64][16]
    const float* W   = (const float*)d_in[1];   // [10][64][16][16]
    float* out = (float*)d_out;                 // [3136][10][16]

    // 10 n * 196 groups of 4 quads (196*4 = 784 = 3136/4); 32 KB dyn LDS
    dim3 grid(1960), block(256);
    hipLaunchKernelGGL(caps_kernel, grid, block, 32768, stream, inp, W, out);
}

// Round 11
// 31.093 us; speedup vs baseline: 1.1704x; 1.0179x over previous
//
#include <hip/hip_runtime.h>
#include <hip/hip_bf16.h>

typedef __attribute__((ext_vector_type(4))) float f32x4;
typedef __attribute__((ext_vector_type(8))) short s16x8;
typedef __attribute__((ext_vector_type(2))) __fp16 h16x2;

// inputs: [3136][64][16] f32, W: [10][64][16][16] f32, out: [3136][10][16] f32.
// Gram-space routing per (pos,n): G = R^T R (MFMA bf16), s0 = (1/64) R^T 1,
// s += G*squash(s) x2, out = squash(s).
//
// R11 = R10 (verified: 2 quads/iter, 2 routing chains, bf16 scatter/b128
// frags, shfl routing) with ONE change: einsum math f32 FMA -> v_dot2_f32_f16
// (f16 mul, f32 accumulate; packed DPP rotations).

template<int CTRL>
__device__ __forceinline__ float dpp_add(float x) {
    int v = __builtin_amdgcn_update_dpp(0, __float_as_int(x), CTRL, 0xF, 0xF, true);
    return x + __int_as_float(v);
}
template<int CTRL>
__device__ __forceinline__ int dpp_mov(int x) {
    return __builtin_amdgcn_update_dpp(0, x, CTRL, 0xF, 0xF, true);
}
__device__ __forceinline__ h16x2 bch(int x) { return __builtin_bit_cast(h16x2, x); }
__device__ __forceinline__ int bci(h16x2 x) { return __builtin_bit_cast(int, x); }

__global__ __launch_bounds__(256, 3) void caps_kernel(
    const float* __restrict__ inp,
    const float* __restrict__ W,
    float* __restrict__ out)
{
    const int tid = threadIdx.x;
    const int w   = tid >> 6;
    const int l   = tid & 63;
    const int n   = blockIdx.x / 196;
    const int qg  = blockIdx.x % 196;
    const int q0  = qg * 4;            // 4 quads per block = 2 double-quad iters

    extern __shared__ __align__(16) char smem[];
    char* res_s = smem;                // res double buffer: 2 x 16KB

    const int i4 = l >> 2;          // row within 16-block
    const int oq = l & 3;           // o-quad / own e-chunk
    const int i_ = w * 16 + i4;     // input capsule 0..63
    const int col = l & 15;
    const int kg  = l >> 4;

    // ---- W straight to regs, rotation-ordered, packed f16 pairs:
    // chunk c=(oq+r)&3 holds e = 4c..4c+3.
    // wpk[r*8 + dd]     = pk( W[e=4c  ][oq*4+dd], W[e=4c+1][oq*4+dd] )
    // wpk[r*8 + 4 + dd] = pk( W[e=4c+2][oq*4+dd], W[e=4c+3][oq*4+dd] )
    const float* wb = W + (size_t)n * 16384 + i_ * 256 + oq * 4;
    h16x2 wpk[32];
#pragma unroll
    for (int r = 0; r < 4; ++r) {
        int c = (oq + r) & 3;
        f32x4 w0 = *(const f32x4*)(wb + (c * 4 + 0) * 16);
        f32x4 w1 = *(const f32x4*)(wb + (c * 4 + 1) * 16);
        f32x4 w2 = *(const f32x4*)(wb + (c * 4 + 2) * 16);
        f32x4 w3 = *(const f32x4*)(wb + (c * 4 + 3) * 16);
#pragma unroll
        for (int dd = 0; dd < 4; ++dd) {
            wpk[r * 8 + dd]     = __builtin_amdgcn_cvt_pkrtz(w0[dd], w1[dd]);
            wpk[r * 8 + 4 + dd] = __builtin_amdgcn_cvt_pkrtz(w2[dd], w3[dd]);
        }
    }

    s16x8 ones;
#pragma unroll
    for (int j = 0; j < 8; ++j) ones[j] = (short)0x3F80;  // bf16 1.0

    // ---- first double-quad inp load (coalesced 16B/lane)
    f32x4 raw[8];
#pragma unroll
    for (int pp = 0; pp < 8; ++pp)
        raw[pp] = *(const f32x4*)(inp + (size_t)q0 * 4096 + pp * 1024 + w * 256 + l * 4);

#pragma unroll
    for (int t = 0; t < 2; ++t) {
        char* rbuf = res_s + (t & 1) * 16384;
        const int qb = q0 + 2 * t;          // first quad of this double-quad

        // ---- einsum (fdot2): res[pp][i_][oq*4+dd] = sum_e inp*W
#pragma unroll
        for (int pp = 0; pp < 8; ++pp) {
            f32x4 a = raw[pp];
            int iA = bci(__builtin_amdgcn_cvt_pkrtz(a[0], a[1]));  // e pair (4oq, 4oq+1)
            int iB = bci(__builtin_amdgcn_cvt_pkrtz(a[2], a[3]));  // e pair (4oq+2, 4oq+3)
            float acc0 = 0.f, acc1 = 0.f, acc2 = 0.f, acc3 = 0.f;

            // r = 0 (own chunk)
            acc0 = __builtin_amdgcn_fdot2(bch(iA), wpk[0], acc0, false);
            acc1 = __builtin_amdgcn_fdot2(bch(iA), wpk[1], acc1, false);
            acc2 = __builtin_amdgcn_fdot2(bch(iA), wpk[2], acc2, false);
            acc3 = __builtin_amdgcn_fdot2(bch(iA), wpk[3], acc3, false);
            acc0 = __builtin_amdgcn_fdot2(bch(iB), wpk[4], acc0, false);
            acc1 = __builtin_amdgcn_fdot2(bch(iB), wpk[5], acc1, false);
            acc2 = __builtin_amdgcn_fdot2(bch(iB), wpk[6], acc2, false);
            acc3 = __builtin_amdgcn_fdot2(bch(iB), wpk[7], acc3, false);
            // r = 1..3: rotate packed pairs within quad
            {
                int jA = dpp_mov<0x39>(iA), jB = dpp_mov<0x39>(iB);
                acc0 = __builtin_amdgcn_fdot2(bch(jA), wpk[8],  acc0, false);
                acc1 = __builtin_amdgcn_fdot2(bch(jA), wpk[9],  acc1, false);
                acc2 = __builtin_amdgcn_fdot2(bch(jA), wpk[10], acc2, false);
                acc3 = __builtin_amdgcn_fdot2(bch(jA), wpk[11], acc3, false);
                acc0 = __builtin_amdgcn_fdot2(bch(jB), wpk[12], acc0, false);
                acc1 = __builtin_amdgcn_fdot2(bch(jB), wpk[13], acc1, false);
                acc2 = __builtin_amdgcn_fdot2(bch(jB), wpk[14], acc2, false);
                acc3 = __builtin_amdgcn_fdot2(bch(jB), wpk[15], acc3, false);
            }
            {
                int jA = dpp_mov<0x4E>(iA), jB = dpp_mov<0x4E>(iB);
                acc0 = __builtin_amdgcn_fdot2(bch(jA), wpk[16], acc0, false);
                acc1 = __builtin_amdgcn_fdot2(bch(jA), wpk[17], acc1, false);
                acc2 = __builtin_amdgcn_fdot2(bch(jA), wpk[18], acc2, false);
                acc3 = __builtin_amdgcn_fdot2(bch(jA), wpk[19], acc3, false);
                acc0 = __builtin_amdgcn_fdot2(bch(jB), wpk[20], acc0, false);
                acc1 = __builtin_amdgcn_fdot2(bch(jB), wpk[21], acc1, false);
                acc2 = __builtin_amdgcn_fdot2(bch(jB), wpk[22], acc2, false);
                acc3 = __builtin_amdgcn_fdot2(bch(jB), wpk[23], acc3, false);
            }
            {
                int jA = dpp_mov<0x93>(iA), jB = dpp_mov<0x93>(iB);
                acc0 = __builtin_amdgcn_fdot2(bch(jA), wpk[24], acc0, false);
                acc1 = __builtin_amdgcn_fdot2(bch(jA), wpk[25], acc1, false);
                acc2 = __builtin_amdgcn_fdot2(bch(jA), wpk[26], acc2, false);
                acc3 = __builtin_amdgcn_fdot2(bch(jA), wpk[27], acc3, false);
                acc0 = __builtin_amdgcn_fdot2(bch(jB), wpk[28], acc0, false);
                acc1 = __builtin_amdgcn_fdot2(bch(jB), wpk[29], acc1, false);
                acc2 = __builtin_amdgcn_fdot2(bch(jB), wpk[30], acc2, false);
                acc3 = __builtin_amdgcn_fdot2(bch(jB), wpk[31], acc3, false);
            }

            // bf16 scatter into [pp][o][i] (chunk-XOR swizzle) — R10-verified
            float accv[4] = {acc0, acc1, acc2, acc3};
#pragma unroll
            for (int dd = 0; dd < 4; ++dd) {
                int o = oq * 4 + dd;
                __hip_bfloat16 bb = __float2bfloat16(accv[dd]);
                int byte = pp * 2048 + o * 128 + (((i_ >> 3) ^ (o & 7)) << 4) + (i_ & 7) * 2;
                *(unsigned short*)(rbuf + byte) = *(unsigned short*)&bb;
            }
        }

        // issue next double-quad loads now; they complete under phase B
        if (t == 0) {
#pragma unroll
            for (int pp = 0; pp < 8; ++pp)
                raw[pp] = *(const f32x4*)(inp + (size_t)(q0 + 2) * 4096 + pp * 1024 + w * 256 + l * 4);
        }

        // one barrier per double-quad (res double-buffered)
        asm volatile("s_waitcnt lgkmcnt(0)" ::: "memory");
        __builtin_amdgcn_s_barrier();
        asm volatile("" ::: "memory");
        __builtin_amdgcn_sched_barrier(0);

        // ---- phase B (R10 verbatim): wave w handles pp = w and pp = w+4
        float s[2];
        f32x4 G[2];
#pragma unroll
        for (int c = 0; c < 2; ++c) {
            const int pp = w + 4 * c;
            s16x8 fr0 = *(const s16x8*)(rbuf + pp * 2048 + col * 128 + (((kg + 0) ^ (col & 7)) << 4));
            s16x8 fr1 = *(const s16x8*)(rbuf + pp * 2048 + col * 128 + (((kg + 4) ^ (col & 7)) << 4));
            f32x4 g  = (f32x4)0.0f;
            f32x4 c2 = (f32x4)0.0f;
            g  = __builtin_amdgcn_mfma_f32_16x16x32_bf16(fr0, fr0, g, 0, 0, 0);
            g  = __builtin_amdgcn_mfma_f32_16x16x32_bf16(fr1, fr1, g, 0, 0, 0);
            c2 = __builtin_amdgcn_mfma_f32_16x16x32_bf16(ones, fr0, c2, 0, 0, 0);
            c2 = __builtin_amdgcn_mfma_f32_16x16x32_bf16(ones, fr1, c2, 0, 0, 0);
            G[c] = g;
            s[c] = c2[0] * (1.0f / 64.0f);
        }

#pragma unroll
        for (int it = 0; it < 2; ++it) {
#pragma unroll
            for (int c = 0; c < 2; ++c) {
                float sn = s[c] * s[c];
                sn = dpp_add<0xB1>(sn);
                sn = dpp_add<0x4E>(sn);
                sn = dpp_add<0x124>(sn);
                sn = dpp_add<0x128>(sn);
                float scale = sqrtf(sn) / (1.0f + sn);
                float v = scale * s[c];
                float v0 = __shfl(v, kg * 4 + 0);
                float v1 = __shfl(v, kg * 4 + 1);
                float v2 = __shfl(v, kg * 4 + 2);
                float v3 = __shfl(v, kg * 4 + 3);
                float acc = G[c][0] * v0 + G[c][1] * v1 + G[c][2] * v2 + G[c][3] * v3;
                acc += __shfl_xor(acc, 16);
                acc += __shfl_xor(acc, 32);
                s[c] += acc;
            }
        }

#pragma unroll
        for (int c = 0; c < 2; ++c) {
            float sn = s[c] * s[c];
            sn = dpp_add<0xB1>(sn);
            sn = dpp_add<0x4E>(sn);
            sn = dpp_add<0x124>(sn);
            sn = dpp_add<0x128>(sn);
            float scale = sqrtf(sn) / (1.0f + sn);
            float v = scale * s[c];
            if (l < 16)
                out[((size_t)((qb + c) * 4 + w) * 10 + n) * 16 + col] = v;
        }
    }
}

extern "C" void kernel_launch(void* const* d_in, const int* in_sizes, int n_in,
                              void* d_out, int out_size, void* d_ws, size_t ws_size,
                              hipStream_t stream) {
    const float* inp = (const float*)d_in[0];   // [3136][64][16]
    const float* W   = (const float*)d_in[1];   // [10][64][16][16]
    float* out = (float*)d_out;                 // [3136][10][16]

    // 10 n * 196 groups of 4 quads (196*4 = 784 = 3136/4); 32 KB dyn LDS
    dim3 grid(1960), block(256);
    hipLaunchKernelGGL(caps_kernel, grid, block, 32768, stream, inp, W, out);
}